// Round 3
// baseline (130.400 us; speedup 1.0000x reference)
//
#include <hip/hip_runtime.h>
#include <math.h>

// Gumbel subset (relaxed top-k) — B=2048 rows, N=8192, K=64 softmax steps.
// Multiplicative reformulation: v_i = exp(s0_i - M0) carried in registers.
// Per step: w = v*rinv(S); kh += w; v = fma(-w, v, v)  [= v*(1-p)].
// R3: THREADS=512/EPT=16 to fit ≤64 regs -> 8 waves/SIMD occupancy;
// sum-of-next-v fused into the update loop (4 partial accumulators).

#define BROWS 2048
#define NCOLS 8192
#define KSTEPS 64

#define THREADS 512
#define EPT (NCOLS / THREADS) // 16 elements per thread, held in registers
#define NWAVE (THREADS / 64)  // 8 waves per block

__global__ __launch_bounds__(THREADS, 8) void gumbel_subset_kernel(
    const float* __restrict__ scores,
    const float* __restrict__ g,
    float* __restrict__ out)
{
    const int row = blockIdx.x;
    const int t = threadIdx.x;
    const float* __restrict__ srow = scores + (size_t)row * NCOLS;
    const float* __restrict__ grow = g + (size_t)row * NCOLS;
    float* __restrict__ orow = out + (size_t)row * NCOLS;

    float v[EPT];
    float kh[EPT];

    // ---- load s0 = scores + g (coalesced float4), track local max ----
    float m = -INFINITY;
#pragma unroll
    for (int c = 0; c < EPT / 4; ++c) {
        const int idx = c * (THREADS * 4) + t * 4;
        const float4 a = *reinterpret_cast<const float4*>(srow + idx);
        const float4 b = *reinterpret_cast<const float4*>(grow + idx);
        const float s0 = a.x + b.x;
        const float s1 = a.y + b.y;
        const float s2 = a.z + b.z;
        const float s3 = a.w + b.w;
        v[c * 4 + 0] = s0;
        v[c * 4 + 1] = s1;
        v[c * 4 + 2] = s2;
        v[c * 4 + 3] = s3;
        m = fmaxf(m, fmaxf(fmaxf(s0, s1), fmaxf(s2, s3)));
    }

    __shared__ float red[2][NWAVE]; // double-buffered per-wave partials
    const int wave = t >> 6;
    const int lane = t & 63;

    // ---- block max reduction (once) ----
#pragma unroll
    for (int off = 32; off > 0; off >>= 1)
        m = fmaxf(m, __shfl_xor(m, off, 64));
    if (lane == 0) red[0][wave] = m;
    __syncthreads();
    m = fmaxf(fmaxf(fmaxf(red[0][0], red[0][1]), fmaxf(red[0][2], red[0][3])),
              fmaxf(fmaxf(red[0][4], red[0][5]), fmaxf(red[0][6], red[0][7])));
    __syncthreads(); // red[0] is re-written by iteration 0 below

    // ---- v = exp(s0 - M0), khot = 0, initial partial sum ----
    float sa = 0.0f, sb = 0.0f, sc = 0.0f, sd = 0.0f;
#pragma unroll
    for (int e = 0; e < EPT; e += 4) {
        v[e + 0] = __expf(v[e + 0] - m);
        v[e + 1] = __expf(v[e + 1] - m);
        v[e + 2] = __expf(v[e + 2] - m);
        v[e + 3] = __expf(v[e + 3] - m);
        kh[e + 0] = 0.0f; kh[e + 1] = 0.0f; kh[e + 2] = 0.0f; kh[e + 3] = 0.0f;
        sa += v[e + 0]; sb += v[e + 1]; sc += v[e + 2]; sd += v[e + 3];
    }

    // ---- K relaxation steps ----
#pragma unroll 2
    for (int it = 0; it < KSTEPS; ++it) {
        float s = (sa + sb) + (sc + sd);
#pragma unroll
        for (int off = 32; off > 0; off >>= 1)
            s += __shfl_xor(s, off, 64);

        const int buf = it & 1;
        if (lane == 0) red[buf][wave] = s;
        __syncthreads();
        const float S = ((red[buf][0] + red[buf][1]) + (red[buf][2] + red[buf][3])) +
                        ((red[buf][4] + red[buf][5]) + (red[buf][6] + red[buf][7]));
        const float rinv = __builtin_amdgcn_rcpf(S);

        sa = 0.0f; sb = 0.0f; sc = 0.0f; sd = 0.0f;
#pragma unroll
        for (int e = 0; e < EPT; e += 4) {
            const float w0 = v[e + 0] * rinv;
            const float w1 = v[e + 1] * rinv;
            const float w2 = v[e + 2] * rinv;
            const float w3 = v[e + 3] * rinv;
            kh[e + 0] += w0; kh[e + 1] += w1; kh[e + 2] += w2; kh[e + 3] += w3;
            v[e + 0] = __builtin_fmaf(-w0, v[e + 0], v[e + 0]);
            v[e + 1] = __builtin_fmaf(-w1, v[e + 1], v[e + 1]);
            v[e + 2] = __builtin_fmaf(-w2, v[e + 2], v[e + 2]);
            v[e + 3] = __builtin_fmaf(-w3, v[e + 3], v[e + 3]);
            sa += v[e + 0]; sb += v[e + 1]; sc += v[e + 2]; sd += v[e + 3];
        }
        // double-buffered red[] -> single barrier per iteration is safe:
        // next write targets the other buffer; the buffer just read is only
        // re-written after the *next* barrier.
    }

    // ---- store khot (coalesced float4) ----
#pragma unroll
    for (int c = 0; c < EPT / 4; ++c) {
        const int idx = c * (THREADS * 4) + t * 4;
        float4 o;
        o.x = kh[c * 4 + 0];
        o.y = kh[c * 4 + 1];
        o.z = kh[c * 4 + 2];
        o.w = kh[c * 4 + 3];
        *reinterpret_cast<float4*>(orow + idx) = o;
    }
}

extern "C" void kernel_launch(void* const* d_in, const int* in_sizes, int n_in,
                              void* d_out, int out_size, void* d_ws, size_t ws_size,
                              hipStream_t stream) {
    const float* scores = (const float*)d_in[0];
    const float* g = (const float*)d_in[1];
    float* out = (float*)d_out;
    (void)in_sizes; (void)n_in; (void)out_size; (void)d_ws; (void)ws_size;

    gumbel_subset_kernel<<<BROWS, THREADS, 0, stream>>>(scores, g, out);
}

// Round 6
// 109.387 us; speedup vs baseline: 1.1921x; 1.1921x over previous
//
#include <hip/hip_runtime.h>
#include <math.h>

// Gumbel subset (relaxed top-k) — B=2048 rows, N=8192, K=64 softmax steps.
// Multiplicative reformulation: v_i = exp(s0_i - M0) carried in registers.
// Per step: w = v*rinv(S); kh += w; v = fma(-w, v, v); s' += v (fused sums).
// R6: ISOLATED test of the register-parking theory. Identical to the proven
// R2/R3 code paths (plain C fma, shfl_xor + scalar LDS partial reduce) with
// ONE change: __launch_bounds__(256,2) -> VGPR budget 256, so the 64-float
// persistent state can live in ARCH VGPRs instead of being parked in AGPRs
// (R1-R3: VGPR_Count 32-56 < 64-float state floor => accvgpr copy tax,
// VALU time ~1.9x the 4-op/elem-iter floor). R4/R5's inline-asm fmacs broke
// numerics and are dropped entirely.

#define BROWS 2048
#define NCOLS 8192
#define KSTEPS 64

#define THREADS 256
#define EPT (NCOLS / THREADS) // 32
#define NWAVE (THREADS / 64)  // 4

__global__ __launch_bounds__(THREADS, 2) void gumbel_subset_kernel(
    const float* __restrict__ scores,
    const float* __restrict__ g,
    float* __restrict__ out)
{
    const int row = blockIdx.x;
    const int t = threadIdx.x;
    const float* __restrict__ srow = scores + (size_t)row * NCOLS;
    const float* __restrict__ grow = g + (size_t)row * NCOLS;
    float* __restrict__ orow = out + (size_t)row * NCOLS;

    float v[EPT];
    float kh[EPT];

    // ---- load s0 = scores + g (coalesced float4), track local max ----
    float m = -INFINITY;
#pragma unroll
    for (int c = 0; c < EPT / 4; ++c) {
        const int idx = c * (THREADS * 4) + t * 4;
        const float4 a = *reinterpret_cast<const float4*>(srow + idx);
        const float4 b = *reinterpret_cast<const float4*>(grow + idx);
        const float s0 = a.x + b.x;
        const float s1 = a.y + b.y;
        const float s2 = a.z + b.z;
        const float s3 = a.w + b.w;
        v[c * 4 + 0] = s0;
        v[c * 4 + 1] = s1;
        v[c * 4 + 2] = s2;
        v[c * 4 + 3] = s3;
        m = fmaxf(m, fmaxf(fmaxf(s0, s1), fmaxf(s2, s3)));
    }

    __shared__ float red[2][NWAVE]; // double-buffered per-wave partials
    const int wave = t >> 6;
    const int lane = t & 63;

    // ---- block max reduction (once) ----
#pragma unroll
    for (int off = 32; off > 0; off >>= 1)
        m = fmaxf(m, __shfl_xor(m, off, 64));
    if (lane == 0) red[0][wave] = m;
    __syncthreads();
    m = fmaxf(fmaxf(red[0][0], red[0][1]), fmaxf(red[0][2], red[0][3]));
    __syncthreads(); // red[0] is re-written by iteration 0 below

    // ---- v = exp(s0 - M0), khot = 0, initial partial sums ----
    float sa = 0.0f, sb = 0.0f, sc = 0.0f, sd = 0.0f;
#pragma unroll
    for (int e = 0; e < EPT; e += 4) {
        v[e + 0] = __expf(v[e + 0] - m);
        v[e + 1] = __expf(v[e + 1] - m);
        v[e + 2] = __expf(v[e + 2] - m);
        v[e + 3] = __expf(v[e + 3] - m);
        kh[e + 0] = 0.0f; kh[e + 1] = 0.0f; kh[e + 2] = 0.0f; kh[e + 3] = 0.0f;
        sa += v[e + 0]; sb += v[e + 1]; sc += v[e + 2]; sd += v[e + 3];
    }

    // ---- K relaxation steps ----
#pragma unroll 2
    for (int it = 0; it < KSTEPS; ++it) {
        float s = (sa + sb) + (sc + sd);
#pragma unroll
        for (int off = 32; off > 0; off >>= 1)
            s += __shfl_xor(s, off, 64);

        const int buf = it & 1;
        if (lane == 0) red[buf][wave] = s;
        __syncthreads();
        const float S = (red[buf][0] + red[buf][1]) + (red[buf][2] + red[buf][3]);
        const float rinv = __builtin_amdgcn_rcpf(S);

        sa = 0.0f; sb = 0.0f; sc = 0.0f; sd = 0.0f;
#pragma unroll
        for (int e = 0; e < EPT; e += 4) {
            const float w0 = v[e + 0] * rinv;
            const float w1 = v[e + 1] * rinv;
            const float w2 = v[e + 2] * rinv;
            const float w3 = v[e + 3] * rinv;
            kh[e + 0] += w0; kh[e + 1] += w1; kh[e + 2] += w2; kh[e + 3] += w3;
            v[e + 0] = __builtin_fmaf(-w0, v[e + 0], v[e + 0]);
            v[e + 1] = __builtin_fmaf(-w1, v[e + 1], v[e + 1]);
            v[e + 2] = __builtin_fmaf(-w2, v[e + 2], v[e + 2]);
            v[e + 3] = __builtin_fmaf(-w3, v[e + 3], v[e + 3]);
            sa += v[e + 0]; sb += v[e + 1]; sc += v[e + 2]; sd += v[e + 3];
        }
        // single barrier per iteration is safe: next write targets the other
        // buffer; this buffer is only re-written after the *next* barrier.
    }

    // ---- store khot (coalesced float4) ----
#pragma unroll
    for (int c = 0; c < EPT / 4; ++c) {
        const int idx = c * (THREADS * 4) + t * 4;
        float4 o;
        o.x = kh[c * 4 + 0];
        o.y = kh[c * 4 + 1];
        o.z = kh[c * 4 + 2];
        o.w = kh[c * 4 + 3];
        *reinterpret_cast<float4*>(orow + idx) = o;
    }
}

extern "C" void kernel_launch(void* const* d_in, const int* in_sizes, int n_in,
                              void* d_out, int out_size, void* d_ws, size_t ws_size,
                              hipStream_t stream) {
    const float* scores = (const float*)d_in[0];
    const float* g = (const float*)d_in[1];
    float* out = (float*)d_out;
    (void)in_sizes; (void)n_in; (void)out_size; (void)d_ws; (void)ws_size;

    gumbel_subset_kernel<<<BROWS, THREADS, 0, stream>>>(scores, g, out);
}

// Round 7
// 103.845 us; speedup vs baseline: 1.2557x; 1.0534x over previous
//
#include <hip/hip_runtime.h>
#include <math.h>

// Gumbel subset (relaxed top-k) — B=2048 rows, N=8192, K=64 softmax steps.
// Multiplicative reformulation: v_i = exp(s0_i - M0), per step:
//   w = v*rinv(S); kh += w; v = fma(-w, v, v); part' = sum(v).
// R7: state (v, kh) and the inner update in PACKED fp16 (v_pk_*_f16):
// 2 elems/instr at f32 issue rate -> op floor halves (55 -> 27 us), and
// register state halves (32 packs) -> higher occupancy to hide the serial
// per-iteration reduce chain (R6: VALUBusy 61%, occupancy 36%).
// S-reduction stays f32 on the R2/R6-proven shfl_xor + LDS-partial path.
// fp16 error budget: ~5e-4/op over 64 iters -> absmax ~0.01-0.06 << 0.117.

typedef _Float16 h2 __attribute__((ext_vector_type(2)));

#define BROWS 2048
#define NCOLS 8192
#define KSTEPS 64

#define THREADS 256
#define EPT (NCOLS / THREADS)  // 32 f32 elements per thread
#define NPAIR (EPT / 2)        // 16 fp16x2 packs
#define NWAVE (THREADS / 64)   // 4

__global__ __launch_bounds__(THREADS, 4) void gumbel_subset_kernel(
    const float* __restrict__ scores,
    const float* __restrict__ g,
    float* __restrict__ out)
{
    const int row = blockIdx.x;
    const int t = threadIdx.x;
    const float* __restrict__ srow = scores + (size_t)row * NCOLS;
    const float* __restrict__ grow = g + (size_t)row * NCOLS;
    float* __restrict__ orow = out + (size_t)row * NCOLS;

    // ---- load s0 = scores + g (coalesced float4), track local max ----
    // local elem k <-> global idx (k/4)*1024 + t*4 + (k%4)
    float s0[EPT];
    float m = -INFINITY;
#pragma unroll
    for (int c = 0; c < EPT / 4; ++c) {
        const int idx = c * (THREADS * 4) + t * 4;
        const float4 a = *reinterpret_cast<const float4*>(srow + idx);
        const float4 b = *reinterpret_cast<const float4*>(grow + idx);
        s0[c * 4 + 0] = a.x + b.x;
        s0[c * 4 + 1] = a.y + b.y;
        s0[c * 4 + 2] = a.z + b.z;
        s0[c * 4 + 3] = a.w + b.w;
        m = fmaxf(m, fmaxf(fmaxf(s0[c * 4 + 0], s0[c * 4 + 1]),
                           fmaxf(s0[c * 4 + 2], s0[c * 4 + 3])));
    }

    __shared__ float red[2][NWAVE]; // double-buffered per-wave partials
    const int wave = t >> 6;
    const int lane = t & 63;

    // ---- block max reduction (once) ----
#pragma unroll
    for (int off = 32; off > 0; off >>= 1)
        m = fmaxf(m, __shfl_xor(m, off, 64));
    if (lane == 0) red[0][wave] = m;
    __syncthreads();
    m = fmaxf(fmaxf(red[0][0], red[0][1]), fmaxf(red[0][2], red[0][3]));
    __syncthreads(); // red[0] is re-written by iteration 0 below

    // ---- v = exp(s0 - M0) packed fp16, kh = 0, initial f32 partial ----
    h2 v[NPAIR];
    h2 kh[NPAIR];
    float part = 0.0f;
#pragma unroll
    for (int p = 0; p < NPAIR; ++p) {
        const float e0 = __expf(s0[2 * p + 0] - m);
        const float e1 = __expf(s0[2 * p + 1] - m);
        v[p] = (h2){(_Float16)e0, (_Float16)e1};
        kh[p] = (h2){(_Float16)0.0f, (_Float16)0.0f};
        part += e0 + e1;
    }

    // ---- K relaxation steps ----
#pragma unroll 2
    for (int it = 0; it < KSTEPS; ++it) {
        float s = part;
#pragma unroll
        for (int off = 32; off > 0; off >>= 1)
            s += __shfl_xor(s, off, 64);

        const int buf = it & 1;
        if (lane == 0) red[buf][wave] = s;
        __syncthreads();
        const float S = (red[buf][0] + red[buf][1]) + (red[buf][2] + red[buf][3]);
        const float rinvf = __builtin_amdgcn_rcpf(S);
        const _Float16 rh = (_Float16)rinvf;
        const h2 rinv2 = (h2){rh, rh};

        h2 a0 = (h2){(_Float16)0.0f, (_Float16)0.0f};
        h2 a1 = a0, a2 = a0, a3 = a0;
#pragma unroll
        for (int p = 0; p < NPAIR; p += 4) {
            const h2 w0 = v[p + 0] * rinv2;
            const h2 w1 = v[p + 1] * rinv2;
            const h2 w2 = v[p + 2] * rinv2;
            const h2 w3 = v[p + 3] * rinv2;
            kh[p + 0] += w0; kh[p + 1] += w1; kh[p + 2] += w2; kh[p + 3] += w3;
            v[p + 0] = __builtin_elementwise_fma(-w0, v[p + 0], v[p + 0]);
            v[p + 1] = __builtin_elementwise_fma(-w1, v[p + 1], v[p + 1]);
            v[p + 2] = __builtin_elementwise_fma(-w2, v[p + 2], v[p + 2]);
            v[p + 3] = __builtin_elementwise_fma(-w3, v[p + 3], v[p + 3]);
            a0 += v[p + 0]; a1 += v[p + 1]; a2 += v[p + 2]; a3 += v[p + 3];
        }
        const h2 a01 = a0 + a1;
        const h2 a23 = a2 + a3;
        const h2 aa = a01 + a23;
        part = (float)aa.x + (float)aa.y;
        // single barrier per iteration is safe: next write targets the other
        // buffer; this buffer is only re-written after the *next* barrier.
    }

    // ---- store khot (coalesced float4; pairs 2c, 2c+1 -> lanes xyzw) ----
#pragma unroll
    for (int c = 0; c < EPT / 4; ++c) {
        const int idx = c * (THREADS * 4) + t * 4;
        float4 o;
        o.x = (float)kh[2 * c + 0].x;
        o.y = (float)kh[2 * c + 0].y;
        o.z = (float)kh[2 * c + 1].x;
        o.w = (float)kh[2 * c + 1].y;
        *reinterpret_cast<float4*>(orow + idx) = o;
    }
}

extern "C" void kernel_launch(void* const* d_in, const int* in_sizes, int n_in,
                              void* d_out, int out_size, void* d_ws, size_t ws_size,
                              hipStream_t stream) {
    const float* scores = (const float*)d_in[0];
    const float* g = (const float*)d_in[1];
    float* out = (float*)d_out;
    (void)in_sizes; (void)n_in; (void)out_size; (void)d_ws; (void)ws_size;

    gumbel_subset_kernel<<<BROWS, THREADS, 0, stream>>>(scores, g, out);
}